// Round 6
// baseline (280.028 us; speedup 1.0000x reference)
//
#include <hip/hip_runtime.h>
#include <math.h>

#define NN 320      // particles
#define DD 64       // dim
#define NPERM 1001  // identity + 1000 permutations
#define KPB 2       // perms per qf block
#define NPG ((NPERM + KPB - 1) / KPB)   // 501 perm-groups
#define RSPLIT 2                        // row chunks per perm-group
#define RCHUNK (NN / RSPLIT)            // 160 rows per block
#define NW 10                           // u32 words per 320-bit mask
#define NPAIRF ((double)(NN * (NN - 1) / 2))   // 51040

// ---------------------------------------------------------------------------
// Math (u in {+-1} since Fv=-1, Bv=+1; PASSING since round 1, absmax 0):
//   d_ab = da_ab + (u_a*u_b)*dh_ab,  da=(dp+dm)/2, dh=(dp-dm)/2
//   SV_ordered = C0 + u^T Dh u - 2 q^T Da q - 2 (qu)^T Dh (qu), C0 = Sum da
//     (diagonal self-cancels: da_rr + dh_rr = 0)
//   SV2 = N*S - |y|^2,  y = Sum_a u_a x_a
// Round-5 post-mortem: structure right, schedule bloated — 5 graph nodes
// (~4-5us each boundary) + qf at 1 block/CU (KPB=4 col cache, lb(512,2)).
// Fix: 2 kernels / 3 nodes. qf absorbs coef (inline bit decode) and final
// (last-block-per-pg combine via threadfence+atomic counter, device scope).
// KPB=2 halves col cache -> lb(512,4), 2 blocks/CU.
// ws: srow@0 (320 f64) | rsda@4096 (320 f64) | cnt@8192 (501 i32) |
//     part@12288 (501*2*8 f64 = 64KB) | ypart@131072 (501*2*2*64 f32) |
//     DAH@1048576 (320*320 float2 = 800KB)
// ---------------------------------------------------------------------------

// Gram row; DAH = {da,dh}; per-row srow/rsda (no atomics); re-zero counters.
__global__ __launch_bounds__(NN) void dah_kernel(const float* __restrict__ data,
                                                 float2* __restrict__ DAH,
                                                 double* __restrict__ srow,
                                                 double* __restrict__ rsda,
                                                 int* __restrict__ cnt) {
    __shared__ float rowa[DD];
    __shared__ double cr[5];
    const int a = blockIdx.x;
    const int t = threadIdx.x;
    if (t == 0) {                       // re-zero completion counters each iter
        for (int i = a; i < NPG; i += NN) cnt[i] = 0;
    }
    if (t < DD) rowa[t] = data[a * DD + t];
    __syncthreads();
    const float* rb = data + t * DD;
    float g = 0.f, sa = 0.f, st = 0.f;
#pragma unroll
    for (int k = 0; k < DD; k += 4) {
        const float4 x = *(const float4*)(rb + k);
        const float r0 = rowa[k], r1 = rowa[k + 1], r2 = rowa[k + 2], r3 = rowa[k + 3];
        g  = fmaf(r0, x.x, g);   g  = fmaf(r1, x.y, g);
        g  = fmaf(r2, x.z, g);   g  = fmaf(r3, x.w, g);
        sa = fmaf(r0, r0, sa);   sa = fmaf(r1, r1, sa);
        sa = fmaf(r2, r2, sa);   sa = fmaf(r3, r3, sa);
        st = fmaf(x.x, x.x, st); st = fmaf(x.y, x.y, st);
        st = fmaf(x.z, x.z, st); st = fmaf(x.w, x.w, st);
    }
    const float sum = sa + st;
    const float dp = sqrtf(fmaxf(fmaf(-2.f, g, sum), 0.f));
    const float dm = sqrtf(fmaxf(fmaf( 2.f, g, sum), 0.f));
    const float da = 0.5f * (dp + dm);
    const float dh = 0.5f * (dp - dm);
    DAH[(size_t)a * NN + t] = make_float2(da, dh);

    double cd = (double)da;
    for (int off = 32; off; off >>= 1) cd += __shfl_down(cd, off, 64);
    const int wid = t >> 6, lane = t & 63;
    if (lane == 0) cr[wid] = cd;
    __syncthreads();
    if (t == 0) {
        double tot = 0.0;
#pragma unroll
        for (int i = 0; i < 5; ++i) tot += cr[i];
        rsda[a] = tot;                 // row-sum of da
        srow[a] = (double)sa;          // |x_a|^2
    }
}

// One block = 2 perms x 160 rows. Inline bit decode; quadratic-form partials;
// y-partials; last block per perm-group combines and writes out.
__global__ __launch_bounds__(512, 4) void qf_kernel(const float* __restrict__ data,
                                                    const int* __restrict__ types,
                                                    const int* __restrict__ perms,
                                                    const float* __restrict__ fermp,
                                                    const float* __restrict__ bosp,
                                                    const float* __restrict__ DAHf,
                                                    const double* __restrict__ srow,
                                                    const double* __restrict__ rsda,
                                                    double* __restrict__ part,
                                                    float* __restrict__ ypart,
                                                    int* __restrict__ cnt,
                                                    float* __restrict__ out) {
    __shared__ unsigned cb[KPB][2 * NW];
    __shared__ __align__(16) float rcoef[RCHUNK * 3 * 4];  // [r][3 float4] {u,q,v,0}
    __shared__ float ysh[KPB][4][DD];
    __shared__ double red[8][6];
    __shared__ double redS[8], redC[8], scal[KPB];
    __shared__ int lastFlag;

    const int pg   = blockIdx.x;
    const int rc   = blockIdx.y;
    const int row0 = rc * RCHUNK;
    const int t    = threadIdx.x;

    // ---- inline coefficient decode (bits in LDS) ----
    if (t < KPB * 2 * NW) ((unsigned*)cb)[t] = 0u;
    __syncthreads();
    const float Fv = *fermp, Bv = *bosp;
    if (t < NN) {
        const int i  = t;
        const int ti = types[i];
#pragma unroll
        for (int k = 0; k < KPB; ++k) {
            int p = pg * KPB + k; if (p >= NPERM) p = NPERM - 1;
            const int a  = (p == 0) ? i : perms[(size_t)(p - 1) * NN + i];
            const int ta = types[a];
            float u = 1.f;
            if (a != i) u = (ti == 0 && ta == 0) ? Fv : ((ti == 1 && ta == 1) ? Bv : 1.f);
            if (u < 0.f) atomicOr(&cb[k][a >> 5], 1u << (a & 31));
            if (ti == 0) atomicOr(&cb[k][NW + (a >> 5)], 1u << (a & 31));
        }
    }
    __syncthreads();

    // Row coefficients for this chunk (stride 48 B; broadcast reads in loop).
    if (t < KPB * RCHUNK) {
        const int k = t / RCHUNK, r = t % RCHUNK;
        const int a = row0 + r;
        const unsigned ubit = (cb[k][a >> 5]        >> (a & 31)) & 1u;
        const unsigned qbit = (cb[k][NW + (a >> 5)] >> (a & 31)) & 1u;
        const float u = ubit ? -1.f : 1.f;
        *(float4*)&rcoef[(r * 3 + k) * 4] =
            make_float4(u, qbit ? 1.f : 0.f, qbit ? u : 0.f, 0.f);
    }

    // Column cache: 8 cols x 3 coefs x 2 perms in VGPRs (48 regs).
    const int strip  = t % 40;
    const int rowoff = t / 40;
    const int col0   = strip * 8;
    float ub[KPB][8], qb[KPB][8], vb[KPB][8];
    if (rowoff < 12) {
#pragma unroll
        for (int k = 0; k < KPB; ++k) {
            const unsigned uw = cb[k][col0 >> 5]        >> (col0 & 31);
            const unsigned qw = cb[k][NW + (col0 >> 5)] >> (col0 & 31);
#pragma unroll
            for (int e = 0; e < 8; ++e) {
                const float u = ((uw >> e) & 1u) ? -1.f : 1.f;
                const bool  q = ((qw >> e) & 1u) != 0u;
                ub[k][e] = u;
                qb[k][e] = q ? 1.f : 0.f;
                vb[k][e] = q ? u : 0.f;
            }
        }
    }
    __syncthreads();

    // ---- main sweep: rows row0..row0+159, cols col0..col0+7 ----
    float A2[KPB] = {0.f, 0.f};   // u^T Dh u
    float A3[KPB] = {0.f, 0.f};   // q^T Da q
    float A4[KPB] = {0.f, 0.f};   // (qu)^T Dh (qu)

    if (rowoff < 12) {
        const float* gp  = DAHf + (size_t)((row0 + rowoff) * NN + col0) * 2;
        const float* app = rcoef + rowoff * 3 * 4;

        auto row_body = [&]() {
            const float4 d0 = *(const float4*)(gp);       // {da,dh,da,dh}
            const float4 d1 = *(const float4*)(gp + 4);
            const float4 d2 = *(const float4*)(gp + 8);
            const float4 d3 = *(const float4*)(gp + 12);
#pragma unroll
            for (int k = 0; k < KPB; ++k) {
                const float4 rp = *(const float4*)(app + k * 4);  // {u_a,q_a,v_a}
                float r2 = ub[k][0] * d0.y;
                float r3 = qb[k][0] * d0.x;
                float r4 = vb[k][0] * d0.y;
                r2 = fmaf(ub[k][1], d0.w, r2); r3 = fmaf(qb[k][1], d0.z, r3); r4 = fmaf(vb[k][1], d0.w, r4);
                r2 = fmaf(ub[k][2], d1.y, r2); r3 = fmaf(qb[k][2], d1.x, r3); r4 = fmaf(vb[k][2], d1.y, r4);
                r2 = fmaf(ub[k][3], d1.w, r2); r3 = fmaf(qb[k][3], d1.z, r3); r4 = fmaf(vb[k][3], d1.w, r4);
                r2 = fmaf(ub[k][4], d2.y, r2); r3 = fmaf(qb[k][4], d2.x, r3); r4 = fmaf(vb[k][4], d2.y, r4);
                r2 = fmaf(ub[k][5], d2.w, r2); r3 = fmaf(qb[k][5], d2.z, r3); r4 = fmaf(vb[k][5], d2.w, r4);
                r2 = fmaf(ub[k][6], d3.y, r2); r3 = fmaf(qb[k][6], d3.x, r3); r4 = fmaf(vb[k][6], d3.y, r4);
                r2 = fmaf(ub[k][7], d3.w, r2); r3 = fmaf(qb[k][7], d3.z, r3); r4 = fmaf(vb[k][7], d3.w, r4);
                A2[k] = fmaf(rp.x, r2, A2[k]);
                A3[k] = fmaf(rp.y, r3, A3[k]);
                A4[k] = fmaf(rp.z, r4, A4[k]);
            }
        };

        for (int it = 0; it < 13; ++it) {     // rows row0 .. row0+155
            row_body();
            gp  += 12 * NN * 2;
            app += 12 * 12;
        }
        if (rowoff < 4) row_body();           // rows row0+156 .. row0+159
    }

    // ---- y-partials over this row chunk (reuses decoded rcoef) ----
    {
        const int k = t >> 8, sub = t & 255;
        const int d = sub & 63, j = sub >> 6;     // 4 row-groups x 64 dims
        float acc = 0.f;
        const int r0 = j * (RCHUNK / 4);
        for (int i = 0; i < RCHUNK / 4; ++i) {
            const int r = r0 + i;
            acc = fmaf(rcoef[(r * 3 + k) * 4], data[(size_t)(row0 + r) * DD + d], acc);
        }
        ysh[k][j][d] = acc;
    }
    __syncthreads();
    if (t < KPB * DD) {
        const int k = t / DD, d = t % DD;
        const float yp = (ysh[k][0][d] + ysh[k][1][d]) + (ysh[k][2][d] + ysh[k][3][d]);
        ypart[(((size_t)pg * RSPLIT + rc) * KPB + k) * DD + d] = yp;
    }

    // ---- A partials: f32 -> f64 -> wave -> cross-wave -> ws ----
    double rd[6];
#pragma unroll
    for (int k = 0; k < KPB; ++k) {
        rd[k]     = (double)A2[k];
        rd[2 + k] = (double)A3[k];
        rd[4 + k] = (double)A4[k];
    }
    for (int off = 32; off; off >>= 1) {
#pragma unroll
        for (int j = 0; j < 6; ++j) rd[j] += __shfl_down(rd[j], off, 64);
    }
    const int wid = t >> 6, lane = t & 63;
    if (lane == 0) {
#pragma unroll
        for (int j = 0; j < 6; ++j) red[wid][j] = rd[j];
    }
    __syncthreads();
    if (t == 0) {
        double* dst = part + ((size_t)pg * RSPLIT + rc) * 8;
#pragma unroll
        for (int j = 0; j < 6; ++j) {
            double v = 0.0;
            for (int w = 0; w < 8; ++w) v += red[w][j];
            dst[j] = v;
        }
    }

    // ---- last-block-per-pg combine ----
    __threadfence();                 // make this block's ws stores device-visible
    __syncthreads();
    if (t == 0) {
        const int old = atomicAdd(&cnt[pg], 1);   // device-scope
        lastFlag = (old == RSPLIT - 1);
    }
    __syncthreads();
    if (!lastFlag) return;
    __threadfence();                 // acquire: other blocks' stores now visible

    // S and C0 (320-wide f64 reduce)
    {
        double sS = 0.0, sC = 0.0;
        if (t < NN) { sS = srow[t]; sC = rsda[t]; }
        for (int off = 32; off; off >>= 1) {
            sS += __shfl_down(sS, off, 64);
            sC += __shfl_down(sC, off, 64);
        }
        if (lane == 0) { redS[wid] = sS; redC[wid] = sC; }
    }
    // |y|^2 per perm: wave k reduces dim axis
    {
        double yy = 0.0;
        if (t < KPB * DD) {
            const int k = t / DD, d = t % DD;
            float yv = 0.f;
#pragma unroll
            for (int rcx = 0; rcx < RSPLIT; ++rcx)
                yv += ypart[(((size_t)pg * RSPLIT + rcx) * KPB + k) * DD + d];
            yy = (double)yv * (double)yv;
        }
        for (int off = 32; off; off >>= 1) yy += __shfl_down(yy, off, 64);
        if (lane == 0 && wid < KPB) scal[wid] = yy;
    }
    __syncthreads();
    if (t == 0) {
        double S = 0.0, C0 = 0.0;
#pragma unroll
        for (int w = 0; w < 8; ++w) { S += redS[w]; C0 += redC[w]; }
        const double* pb = part + (size_t)pg * RSPLIT * 8;
#pragma unroll
        for (int k = 0; k < KPB; ++k) {
            const int p = pg * KPB + k;
            if (p < NPERM) {
                double T2 = 0.0, T3 = 0.0, T4 = 0.0;
#pragma unroll
                for (int rcx = 0; rcx < RSPLIT; ++rcx) {
                    T2 += pb[rcx * 8 + 0 + k];
                    T3 += pb[rcx * 8 + 2 + k];
                    T4 += pb[rcx * 8 + 4 + k];
                }
                const double SV  = 0.5 * (C0 + T2 - 2.0 * T3 - 2.0 * T4);
                const double SV2 = (double)NN * S - scal[k];
                out[p] = (float)((SV2 - SV * SV / NPAIRF) / (NPAIRF - 1.0));
            }
        }
    }
}

extern "C" void kernel_launch(void* const* d_in, const int* in_sizes, int n_in,
                              void* d_out, int out_size, void* d_ws, size_t ws_size,
                              hipStream_t stream) {
    const float* data  = (const float*)d_in[0];
    const float* fermp = (const float*)d_in[1];
    const float* bosp  = (const float*)d_in[2];
    const int*   types = (const int*)d_in[3];
    const int*   perms = (const int*)d_in[4];
    float* out = (float*)d_out;

    double* srow  = (double*)d_ws;                       // 320 f64
    double* rsda  = (double*)((char*)d_ws + 4096);       // 320 f64
    int*    cnt   = (int*)((char*)d_ws + 8192);          // 501 i32
    double* part  = (double*)((char*)d_ws + 12288);      // 501*2*8 f64 = 64 KB
    float*  ypart = (float*)((char*)d_ws + 131072);      // 501*2*2*64 f32 = 513 KB
    float2* DAH   = (float2*)((char*)d_ws + 1048576);    // 320*320 float2 = 800 KB

    dah_kernel<<<NN, NN, 0, stream>>>(data, DAH, srow, rsda, cnt);
    qf_kernel<<<dim3(NPG, RSPLIT), 512, 0, stream>>>(data, types, perms, fermp, bosp,
                                                     (const float*)DAH, srow, rsda,
                                                     part, ypart, cnt, out);
}

// Round 7
// 94.291 us; speedup vs baseline: 2.9698x; 2.9698x over previous
//
#include <hip/hip_runtime.h>
#include <math.h>

#define NN 320      // particles
#define DD 64       // dim
#define NPERM 1001  // identity + 1000 permutations
#define KPB 4       // perms per qf block
#define NBLK ((NPERM + KPB - 1) / KPB)   // 251 blocks = 1 per CU, one round
#define NW 10                            // u32 words per 320-bit mask
#define NPAIRF ((double)(NN * (NN - 1) / 2))   // 51040

// ---------------------------------------------------------------------------
// Math (u in {+-1} since Fv=-1, Bv=+1; PASSING rounds 1,2,3,5,6 absmax 0):
//   d_ab = da_ab + (u_a*u_b)*dh_ab,  da=(dp+dm)/2, dh=(dp-dm)/2
//   SV_ordered = C0 + u^T Dh u - 2 q^T Da q - 2 (qu)^T Dh (qu), C0 = Sum da
//   SV2 = N*S - |y|^2,  y = Sum_a u_a x_a
// Round-6 post-mortem: __launch_bounds__(512,4) -> VGPR 44 -> col cache in
// scratch -> 217us at 6% VALUBusy. Rule (2x confirmed): min-waves>=4 kills
// this kernel; (512,2) gives the healthy ~128-150 VGPR allocation.
// This round: ONE block per 4 perms, FULL 320-row sweep, 251 blocks = 1/CU,
// zero cross-block sync (no RSPLIT/threadfence/counters). Inline bit decode,
// y + S + C0 + out all in-block. Register double-buffer prefetch on the DAH
// stream hides L2 latency at single-block occupancy.
// ws: srow@0 (320 f64) | rsda@4096 (320 f64) | DAH@1048576 (800KB)
// ---------------------------------------------------------------------------

// Gram row; DAH = {da,dh}; per-row srow/rsda partials (no atomics).
__global__ __launch_bounds__(NN) void dah_kernel(const float* __restrict__ data,
                                                 float2* __restrict__ DAH,
                                                 double* __restrict__ srow,
                                                 double* __restrict__ rsda) {
    __shared__ float rowa[DD];
    __shared__ double cr[5];
    const int a = blockIdx.x;
    const int t = threadIdx.x;
    if (t < DD) rowa[t] = data[a * DD + t];
    __syncthreads();
    const float* rb = data + t * DD;
    float g = 0.f, sa = 0.f, st = 0.f;
#pragma unroll
    for (int k = 0; k < DD; k += 4) {
        const float4 x = *(const float4*)(rb + k);
        const float r0 = rowa[k], r1 = rowa[k + 1], r2 = rowa[k + 2], r3 = rowa[k + 3];
        g  = fmaf(r0, x.x, g);   g  = fmaf(r1, x.y, g);
        g  = fmaf(r2, x.z, g);   g  = fmaf(r3, x.w, g);
        sa = fmaf(r0, r0, sa);   sa = fmaf(r1, r1, sa);
        sa = fmaf(r2, r2, sa);   sa = fmaf(r3, r3, sa);
        st = fmaf(x.x, x.x, st); st = fmaf(x.y, x.y, st);
        st = fmaf(x.z, x.z, st); st = fmaf(x.w, x.w, st);
    }
    const float sum = sa + st;
    const float dp = sqrtf(fmaxf(fmaf(-2.f, g, sum), 0.f));
    const float dm = sqrtf(fmaxf(fmaf( 2.f, g, sum), 0.f));
    const float da = 0.5f * (dp + dm);
    const float dh = 0.5f * (dp - dm);
    DAH[(size_t)a * NN + t] = make_float2(da, dh);

    double cd = (double)da;
    for (int off = 32; off; off >>= 1) cd += __shfl_down(cd, off, 64);
    const int wid = t >> 6, lane = t & 63;
    if (lane == 0) cr[wid] = cd;
    __syncthreads();
    if (t == 0) {
        double tot = 0.0;
#pragma unroll
        for (int i = 0; i < 5; ++i) tot += cr[i];
        rsda[a] = tot;                 // row-sum of da
        srow[a] = (double)sa;          // |x_a|^2
    }
}

// One block = 4 perms, all 320 rows. 512 thr = 40 col-strips x 12 rowoffs.
// Per row-iter/perm: broadcast LDS float4 + (shared) 4 global float4 (DAH,
// prefetched one row ahead into registers) + 27 fma. Self-contained epilogue.
__global__ __launch_bounds__(512, 2) void qf_kernel(const float* __restrict__ data,
                                                    const int* __restrict__ types,
                                                    const int* __restrict__ perms,
                                                    const float* __restrict__ fermp,
                                                    const float* __restrict__ bosp,
                                                    const float* __restrict__ DAHf,
                                                    const double* __restrict__ srow,
                                                    const double* __restrict__ rsda,
                                                    float* __restrict__ out) {
    __shared__ unsigned cb[KPB][2 * NW];
    __shared__ __align__(16) float rcoef[NN * 5 * 4];  // [r][k pad5] {u,q,v,0} 25.6KB
    __shared__ float ysh[KPB][2][DD];
    __shared__ double red[8][12];
    __shared__ double redS[8], redC[8], scal[KPB];

    const int pg = blockIdx.x;
    const int t  = threadIdx.x;

    // ---- inline coefficient decode (bits in LDS) ----
    if (t < KPB * 2 * NW) ((unsigned*)cb)[t] = 0u;
    __syncthreads();
    const float Fv = *fermp, Bv = *bosp;
    if (t < NN) {
        const int i  = t;
        const int ti = types[i];
#pragma unroll
        for (int k = 0; k < KPB; ++k) {
            int p = pg * KPB + k; if (p >= NPERM) p = NPERM - 1;
            const int a  = (p == 0) ? i : perms[(size_t)(p - 1) * NN + i];
            const int ta = types[a];
            float u = 1.f;
            if (a != i) u = (ti == 0 && ta == 0) ? Fv : ((ti == 1 && ta == 1) ? Bv : 1.f);
            if (u < 0.f) atomicOr(&cb[k][a >> 5], 1u << (a & 31));
            if (ti == 0) atomicOr(&cb[k][NW + (a >> 5)], 1u << (a & 31));
        }
    }
    __syncthreads();

    // All-row coefficients, stride 5 float4 = 80 B (conflict-free broadcasts).
    for (int j = t; j < NN * KPB; j += 512) {
        const int r = j >> 2, k = j & 3;
        const unsigned ubit = (cb[k][r >> 5]        >> (r & 31)) & 1u;
        const unsigned qbit = (cb[k][NW + (r >> 5)] >> (r & 31)) & 1u;
        const float u = ubit ? -1.f : 1.f;
        *(float4*)&rcoef[(r * 5 + k) * 4] =
            make_float4(u, qbit ? 1.f : 0.f, qbit ? u : 0.f, 0.f);
    }

    // Column cache: 8 cols x 3 coefs x 4 perms in VGPRs (96 regs).
    const int strip  = t % 40;
    const int rowoff = t / 40;
    const int col0   = strip * 8;
    float ub[KPB][8], qb[KPB][8], vb[KPB][8];
    if (rowoff < 12) {
#pragma unroll
        for (int k = 0; k < KPB; ++k) {
            const unsigned uw = cb[k][col0 >> 5]        >> (col0 & 31);
            const unsigned qw = cb[k][NW + (col0 >> 5)] >> (col0 & 31);
#pragma unroll
            for (int e = 0; e < 8; ++e) {
                const float u = ((uw >> e) & 1u) ? -1.f : 1.f;
                const bool  q = ((qw >> e) & 1u) != 0u;
                ub[k][e] = u;
                qb[k][e] = q ? 1.f : 0.f;
                vb[k][e] = q ? u : 0.f;
            }
        }
    }
    __syncthreads();

    // ---- main sweep: rows 0..319 with one-row register prefetch ----
    float A2[KPB] = {0.f, 0.f, 0.f, 0.f};   // u^T Dh u
    float A3[KPB] = {0.f, 0.f, 0.f, 0.f};   // q^T Da q
    float A4[KPB] = {0.f, 0.f, 0.f, 0.f};   // (qu)^T Dh (qu)

    if (rowoff < 12) {
        const int STRIDE = 12 * NN * 2;
        const float* gp  = DAHf + (size_t)(rowoff * NN + col0) * 2;
        const float* app = rcoef + rowoff * 20;
        float4 c0 = *(const float4*)(gp);
        float4 c1 = *(const float4*)(gp + 4);
        float4 c2 = *(const float4*)(gp + 8);
        float4 c3 = *(const float4*)(gp + 12);

        auto compute = [&](const float* ap) {
#pragma unroll
            for (int k = 0; k < KPB; ++k) {
                const float4 rp = *(const float4*)(ap + k * 4);  // {u_a,q_a,v_a}
                float r2 = ub[k][0] * c0.y;
                float r3 = qb[k][0] * c0.x;
                float r4 = vb[k][0] * c0.y;
                r2 = fmaf(ub[k][1], c0.w, r2); r3 = fmaf(qb[k][1], c0.z, r3); r4 = fmaf(vb[k][1], c0.w, r4);
                r2 = fmaf(ub[k][2], c1.y, r2); r3 = fmaf(qb[k][2], c1.x, r3); r4 = fmaf(vb[k][2], c1.y, r4);
                r2 = fmaf(ub[k][3], c1.w, r2); r3 = fmaf(qb[k][3], c1.z, r3); r4 = fmaf(vb[k][3], c1.w, r4);
                r2 = fmaf(ub[k][4], c2.y, r2); r3 = fmaf(qb[k][4], c2.x, r3); r4 = fmaf(vb[k][4], c2.y, r4);
                r2 = fmaf(ub[k][5], c2.w, r2); r3 = fmaf(qb[k][5], c2.z, r3); r4 = fmaf(vb[k][5], c2.w, r4);
                r2 = fmaf(ub[k][6], c3.y, r2); r3 = fmaf(qb[k][6], c3.x, r3); r4 = fmaf(vb[k][6], c3.y, r4);
                r2 = fmaf(ub[k][7], c3.w, r2); r3 = fmaf(qb[k][7], c3.z, r3); r4 = fmaf(vb[k][7], c3.w, r4);
                A2[k] = fmaf(rp.x, r2, A2[k]);
                A3[k] = fmaf(rp.y, r3, A3[k]);
                A4[k] = fmaf(rp.z, r4, A4[k]);
            }
        };

#pragma unroll 2
        for (int it = 0; it < 26; ++it) {
            const float* gq = gp + STRIDE;
            if (it == 25 && rowoff >= 8) gq = gp;   // no valid next row
            const float4 n0 = *(const float4*)(gq);
            const float4 n1 = *(const float4*)(gq + 4);
            const float4 n2 = *(const float4*)(gq + 8);
            const float4 n3 = *(const float4*)(gq + 12);
            compute(app);
            c0 = n0; c1 = n1; c2 = n2; c3 = n3;
            gp = gq; app += 240;
        }
        if (rowoff < 8) compute(app);               // rows 312..319
    }

    // ---- y partials: 4 perms x 2 row-halves x 64 dims ----
    {
        const int k = t >> 7, sub = t & 127;
        const int j = sub >> 6, d = sub & 63;
        float acc = 0.f;
        const int r0 = j * (NN / 2);
        for (int r = r0; r < r0 + NN / 2; ++r)
            acc = fmaf(rcoef[(r * 5 + k) * 4], data[(size_t)r * DD + d], acc);
        ysh[k][j][d] = acc;
    }

    // ---- A partials: f32 -> f64 -> wave -> cross-wave LDS ----
    double rd[12];
#pragma unroll
    for (int k = 0; k < KPB; ++k) {
        rd[k]     = (double)A2[k];
        rd[4 + k] = (double)A3[k];
        rd[8 + k] = (double)A4[k];
    }
    for (int off = 32; off; off >>= 1) {
#pragma unroll
        for (int j = 0; j < 12; ++j) rd[j] += __shfl_down(rd[j], off, 64);
    }
    const int wid = t >> 6, lane = t & 63;
    if (lane == 0) {
#pragma unroll
        for (int j = 0; j < 12; ++j) red[wid][j] = rd[j];
    }

    // ---- S and C0 (320-wide f64 reduce; per-block, tiny) ----
    {
        double sS = 0.0, sC = 0.0;
        if (t < NN) { sS = srow[t]; sC = rsda[t]; }
        for (int off = 32; off; off >>= 1) {
            sS += __shfl_down(sS, off, 64);
            sC += __shfl_down(sC, off, 64);
        }
        if (lane == 0) { redS[wid] = sS; redC[wid] = sC; }
    }
    __syncthreads();

    // ---- |y|^2: wave k reduces dim axis for perm k ----
    if (t < KPB * 64) {
        const int k = t >> 6, d = t & 63;
        const float yv = ysh[k][0][d] + ysh[k][1][d];
        double yy = (double)yv * (double)yv;
        for (int off = 32; off; off >>= 1) yy += __shfl_down(yy, off, 64);
        if ((t & 63) == 0) scal[k] = yy;
    }
    __syncthreads();

    if (t == 0) {
        double S = 0.0, C0 = 0.0;
#pragma unroll
        for (int w = 0; w < 8; ++w) { S += redS[w]; C0 += redC[w]; }
#pragma unroll
        for (int k = 0; k < KPB; ++k) {
            const int p = pg * KPB + k;
            if (p < NPERM) {
                double T2 = 0.0, T3 = 0.0, T4 = 0.0;
#pragma unroll
                for (int w = 0; w < 8; ++w) {
                    T2 += red[w][k];
                    T3 += red[w][4 + k];
                    T4 += red[w][8 + k];
                }
                const double SV  = 0.5 * (C0 + T2 - 2.0 * T3 - 2.0 * T4);
                const double SV2 = (double)NN * S - scal[k];
                out[p] = (float)((SV2 - SV * SV / NPAIRF) / (NPAIRF - 1.0));
            }
        }
    }
}

extern "C" void kernel_launch(void* const* d_in, const int* in_sizes, int n_in,
                              void* d_out, int out_size, void* d_ws, size_t ws_size,
                              hipStream_t stream) {
    const float* data  = (const float*)d_in[0];
    const float* fermp = (const float*)d_in[1];
    const float* bosp  = (const float*)d_in[2];
    const int*   types = (const int*)d_in[3];
    const int*   perms = (const int*)d_in[4];
    float* out = (float*)d_out;

    double* srow = (double*)d_ws;                       // 320 f64
    double* rsda = (double*)((char*)d_ws + 4096);       // 320 f64
    float2* DAH  = (float2*)((char*)d_ws + 1048576);    // 320*320 float2 = 800 KB

    dah_kernel<<<NN, NN, 0, stream>>>(data, DAH, srow, rsda);
    qf_kernel<<<NBLK, 512, 0, stream>>>(data, types, perms, fermp, bosp,
                                        (const float*)DAH, srow, rsda, out);
}